// Round 10
// baseline (1271.918 us; speedup 1.0000x reference)
//
#include <hip/hip_runtime.h>
#include <math.h>

#define N_NODES 100000
#define N_EDGES 1600000
#define DIM     128
#define NCLS    64
#define ALPHA   0.1f

#define SCAN_B  98                 // ceil(100000/1024)
#define NB      391                // ceil(100000/256) dst-buckets of 256 nodes
#define NF      ((size_t)N_NODES * DIM)
#define STRIPES (N_NODES / 16)     // 6250 exact
#define CHUNK   2048               // edges per partition block

typedef __attribute__((ext_vector_type(8))) short  bf16x8;
typedef __attribute__((ext_vector_type(4))) float  f32x4;

// ---- bf16 helpers (storage only; accumulation fp32) ----
__device__ __forceinline__ float bf2f(unsigned short u) {
    return __uint_as_float((unsigned int)u << 16);
}
__device__ __forceinline__ float2 bf2f2(ushort2 u) {
    return make_float2(bf2f(u.x), bf2f(u.y));
}
__device__ __forceinline__ unsigned short f2bf(float x) {
    unsigned int u = __float_as_uint(x);
    u += 0x7FFFu + ((u >> 16) & 1u);          // round-to-nearest-even
    return (unsigned short)(u >> 16);
}
__device__ __forceinline__ ushort2 f2bf2(float2 v) {
    return make_ushort2(f2bf(v.x), f2bf(v.y));
}

// ================= bucketed CSR build =================
// bucket = dst >> 8 (256 nodes/bucket). ebuf entry: x = src | dst_local<<17, y = 0.9*w (fp32).

__global__ __launch_bounds__(256) void k_hist(const int* __restrict__ dst,
                                              int* __restrict__ bucket_cnt) {
    __shared__ int hist[NB];
    int t = threadIdx.x;
    for (int b = t; b < NB; b += 256) hist[b] = 0;
    __syncthreads();
    int base = blockIdx.x * CHUNK;
    int end = min(base + CHUNK, N_EDGES);
    for (int i = base + t; i < end; i += 256)
        atomicAdd(&hist[dst[i] >> 8], 1);
    __syncthreads();
    for (int b = t; b < NB; b += 256)
        if (hist[b]) atomicAdd(&bucket_cnt[b], hist[b]);
}

__global__ __launch_bounds__(512) void k_scanb(const int* __restrict__ bucket_cnt,
                                               int* __restrict__ bucket_base,
                                               int* __restrict__ bucket_cursor) {
    __shared__ int s[512];
    int t = threadIdx.x;
    int v = (t < NB) ? bucket_cnt[t] : 0;
    s[t] = v;
    __syncthreads();
    for (int off = 1; off < 512; off <<= 1) {
        int u = (t >= off) ? s[t - off] : 0;
        __syncthreads();
        s[t] += u;
        __syncthreads();
    }
    if (t < NB) {
        int base = s[t] - v;
        bucket_base[t] = base;
        bucket_cursor[t] = base;
    }
    if (t == 0) bucket_base[NB] = N_EDGES;
}

__global__ __launch_bounds__(256) void k_part(const int* __restrict__ src,
                                              const int* __restrict__ dst,
                                              const float* __restrict__ ew,
                                              int* __restrict__ bucket_cursor,
                                              int2* __restrict__ ebuf) {
    __shared__ int lhist[NB], gbase[NB];
    int t = threadIdx.x;
    for (int b = t; b < NB; b += 256) lhist[b] = 0;
    __syncthreads();
    int base = blockIdx.x * CHUNK;
    int end = min(base + CHUNK, N_EDGES);
    for (int i = base + t; i < end; i += 256)
        atomicAdd(&lhist[dst[i] >> 8], 1);
    __syncthreads();
    for (int b = t; b < NB; b += 256) {
        int c = lhist[b];
        gbase[b] = c ? atomicAdd(&bucket_cursor[b], c) : 0;
        lhist[b] = 0;
    }
    __syncthreads();
    for (int i = base + t; i < end; i += 256) {
        int d = dst[i];
        int b = d >> 8;
        int r = atomicAdd(&lhist[b], 1);
        ebuf[gbase[b] + r] = make_int2(src[i] | ((d & 255) << 17),
                                       __float_as_int((1.0f - ALPHA) * ew[i]));
    }
}

// per-bucket degree via LDS counters (no global atomics)
__global__ __launch_bounds__(256) void k_deg(const int2* __restrict__ ebuf,
                                             const int* __restrict__ bucket_base,
                                             int* __restrict__ deg) {
    __shared__ int cnt[256];
    int t = threadIdx.x, b = blockIdx.x;
    cnt[t] = 0;
    __syncthreads();
    int beg = bucket_base[b], end = bucket_base[b + 1];
    for (int i = beg + t; i < end; i += 256)
        atomicAdd(&cnt[ebuf[i].x >> 17], 1);
    __syncthreads();
    int node = b * 256 + t;
    if (node < N_NODES) deg[node] = cnt[t];
}

__global__ __launch_bounds__(1024) void k_scan1(const int* __restrict__ deg,
                                                int* __restrict__ row_ptr,
                                                int* __restrict__ blocksum) {
    __shared__ int s[1024];
    int t = threadIdx.x;
    int i = blockIdx.x * 1024 + t;
    int v = (i < N_NODES) ? deg[i] : 0;
    s[t] = v;
    __syncthreads();
    for (int off = 1; off < 1024; off <<= 1) {
        int u = (t >= off) ? s[t - off] : 0;
        __syncthreads();
        s[t] += u;
        __syncthreads();
    }
    if (i < N_NODES) row_ptr[i] = s[t] - v;
    if (t == 1023) blocksum[blockIdx.x] = s[1023];
}

__global__ __launch_bounds__(128) void k_scan2(int* __restrict__ blocksum) {
    __shared__ int s[128];
    int t = threadIdx.x;
    int v = (t < SCAN_B) ? blocksum[t] : 0;
    s[t] = v;
    __syncthreads();
    for (int off = 1; off < 128; off <<= 1) {
        int u = (t >= off) ? s[t - off] : 0;
        __syncthreads();
        s[t] += u;
        __syncthreads();
    }
    if (t < SCAN_B) blocksum[t] = s[t] - v;
}

__global__ __launch_bounds__(1024) void k_scan3(int* __restrict__ row_ptr,
                                                const int* __restrict__ blocksum) {
    int t = threadIdx.x;
    int i = blockIdx.x * 1024 + t;
    if (i < N_NODES) row_ptr[i] += blocksum[blockIdx.x];
    if (i == 0) row_ptr[N_NODES] = N_EDGES;
}

// per-bucket counting-sort scatter; LDS cursors; colw packed 4B/edge:
// bits 31..15 = src (17b), bits 14..0 = bf16((1-a)*w) >> 1  (w>=0, e8m6)
__global__ __launch_bounds__(256) void k_scatter2(const int2* __restrict__ ebuf,
                                                  const int* __restrict__ bucket_base,
                                                  const int* __restrict__ row_ptr,
                                                  unsigned int* __restrict__ colw) {
    __shared__ int lcur[256];
    int t = threadIdx.x, b = blockIdx.x;
    int node = b * 256 + t;
    lcur[t] = (node < N_NODES) ? row_ptr[node] : 0;
    __syncthreads();
    int beg = bucket_base[b], end = bucket_base[b + 1];
    for (int i = beg + t; i < end; i += 256) {
        int2 e = ebuf[i];
        int pos = atomicAdd(&lcur[e.x >> 17], 1);
        unsigned int wb = (unsigned int)f2bf(__int_as_float(e.y)) >> 1;
        colw[pos] = ((unsigned int)(e.x & 0x1FFFF) << 15) | wb;
    }
}

// ===== weight pack: fp32 -> bf16 B-fragment order =====
__global__ void k_prepw(const float* __restrict__ gcnw, const float* __restrict__ wout,
                        const float* __restrict__ win, unsigned short* __restrict__ wp) {
    int tid = blockIdx.x * 256 + threadIdx.x;
    if (tid < 65536) {
        int l = tid >> 14;
        int r = tid & 16383;
        int j = r & 7, lane = (r >> 3) & 63, ch = (r >> 9) & 3, nt = r >> 11;
        int n = nt * 16 + (lane & 15);
        int k = ch * 32 + (lane >> 4) * 8 + j;
        wp[tid] = f2bf(gcnw[l * 16384 + k * 128 + n]);
    } else if (tid < 73728) {
        int r = tid - 65536;
        int j = r & 7, lane = (r >> 3) & 63, ch = (r >> 9) & 3, nt = r >> 11; // nt 0..3
        int n = nt * 16 + (lane & 15);
        int k = ch * 32 + (lane >> 4) * 8 + j;
        wp[tid] = f2bf(wout[k * 64 + n]);
    } else if (tid < 90112) {
        int r = tid - 73728;
        int j = r & 7, lane = (r >> 3) & 63, ch = (r >> 9) & 3, nt = r >> 11; // nt 0..7
        int n = nt * 16 + (lane & 15);
        int k = ch * 32 + (lane >> 4) * 8 + j;
        wp[tid] = f2bf(win[k * 128 + n]);
    }
}

// ===== XCD-sliced SpMM gather =====
// slice s = blockIdx&7 (pinned to XCD s by round-robin dispatch) owns dims
// [16s,16s+16). Per-XCD gather working set = 100K*32B = 3.2MB -> L2-resident.
// Block: 256 thr = 32 nodes x 8 lanes (ushort2 each). colw nontemporal (stream),
// out nontemporal (consumed by another XCD anyway).
__global__ __launch_bounds__(256, 8) void k_spmm_xcd(
    const int* __restrict__ row_ptr, const unsigned int* __restrict__ colw,
    const unsigned short* __restrict__ h, const unsigned short* __restrict__ h0,
    unsigned short* __restrict__ out) {
    int s = blockIdx.x & 7;
    int g = blockIdx.x >> 3;
    int t = threadIdx.x;
    int node = g * 32 + (t >> 3);          // 3125*32 = 100000 exact
    int doff = s * 16 + (t & 7) * 2;
    const unsigned short* hp = h + doff;
    int beg = row_ptr[node], end = row_ptr[node + 1];

    float2 z = bf2f2(*(const ushort2*)(h0 + (size_t)node * DIM + doff));
    float2 acc = make_float2(ALPHA * z.x, ALPHA * z.y);

    int e = beg;
    for (; e + 3 < end; e += 4) {
        unsigned int c0 = __builtin_nontemporal_load(colw + e);
        unsigned int c1 = __builtin_nontemporal_load(colw + e + 1);
        unsigned int c2 = __builtin_nontemporal_load(colw + e + 2);
        unsigned int c3 = __builtin_nontemporal_load(colw + e + 3);
        float2 v0 = bf2f2(*(const ushort2*)(hp + (size_t)(c0 >> 15) * DIM));
        float2 v1 = bf2f2(*(const ushort2*)(hp + (size_t)(c1 >> 15) * DIM));
        float2 v2 = bf2f2(*(const ushort2*)(hp + (size_t)(c2 >> 15) * DIM));
        float2 v3 = bf2f2(*(const ushort2*)(hp + (size_t)(c3 >> 15) * DIM));
        float w0 = __uint_as_float((c0 & 0x7FFFu) << 17);
        float w1 = __uint_as_float((c1 & 0x7FFFu) << 17);
        float w2 = __uint_as_float((c2 & 0x7FFFu) << 17);
        float w3 = __uint_as_float((c3 & 0x7FFFu) << 17);
        acc.x += w0 * v0.x + w1 * v1.x + w2 * v2.x + w3 * v3.x;
        acc.y += w0 * v0.y + w1 * v1.y + w2 * v2.y + w3 * v3.y;
    }
    for (; e < end; e++) {
        unsigned int c0 = __builtin_nontemporal_load(colw + e);
        float2 v0 = bf2f2(*(const ushort2*)(hp + (size_t)(c0 >> 15) * DIM));
        float w0 = __uint_as_float((c0 & 0x7FFFu) << 17);
        acc.x += w0 * v0.x;
        acc.y += w0 * v0.y;
    }
    // pack two bf16 into one uint for nontemporal store (builtin rejects ushort2)
    unsigned int packed = (unsigned int)f2bf(acc.x) | ((unsigned int)f2bf(acc.y) << 16);
    __builtin_nontemporal_store(packed,
        (unsigned int*)(out + (size_t)node * DIM + doff));
}

// ===== MFMA input GEMM: h0 = relu(x @ W_in + b)  (x fp32 -> bf16 in-reg) =====
__global__ __launch_bounds__(256) void k_in_mfma(
    const float* __restrict__ x, const unsigned short* __restrict__ wp,
    const float* __restrict__ b_in, unsigned short* __restrict__ h0) {
    int wave = threadIdx.x >> 6, lane = threadIdx.x & 63;
    int stripe = blockIdx.x * 4 + wave;
    if (stripe >= STRIPES) return;
    int r0 = stripe * 16;
    int m = lane & 15, q = lane >> 4;

    f32x4 acc[8];
    #pragma unroll
    for (int nt = 0; nt < 8; nt++) acc[nt] = (f32x4){0.f, 0.f, 0.f, 0.f};

    const float* xr = x + (size_t)(r0 + m) * DIM + q * 8;
    #pragma unroll
    for (int ch = 0; ch < 4; ch++) {
        float4 a0 = *(const float4*)(xr + ch * 32);
        float4 a1 = *(const float4*)(xr + ch * 32 + 4);
        bf16x8 a;
        a[0] = (short)f2bf(a0.x); a[1] = (short)f2bf(a0.y);
        a[2] = (short)f2bf(a0.z); a[3] = (short)f2bf(a0.w);
        a[4] = (short)f2bf(a1.x); a[5] = (short)f2bf(a1.y);
        a[6] = (short)f2bf(a1.z); a[7] = (short)f2bf(a1.w);
        #pragma unroll
        for (int nt = 0; nt < 8; nt++) {
            bf16x8 b = *(const bf16x8*)(wp + (((nt * 4 + ch) * 64 + lane) << 3));
            acc[nt] = __builtin_amdgcn_mfma_f32_16x16x32_bf16(a, b, acc[nt], 0, 0, 0);
        }
    }

    #pragma unroll
    for (int nt = 0; nt < 8; nt++) {
        int col = nt * 16 + m;
        float bias = b_in[col];
        #pragma unroll
        for (int r = 0; r < 4; r++) {
            int row = r0 + q * 4 + r;
            h0[(size_t)row * DIM + col] = f2bf(fmaxf(acc[nt][r] + bias, 0.f));
        }
    }
}

// ===== MFMA layer GEMM: h = relu(theta*(s@W) + (1-theta)*s + hprev) =====
__global__ __launch_bounds__(256) void k_layer_mfma(
    const unsigned short* __restrict__ s_in, const unsigned short* __restrict__ hprev,
    const unsigned short* __restrict__ wp, unsigned short* __restrict__ hout,
    float theta) {
    int wave = threadIdx.x >> 6, lane = threadIdx.x & 63;
    int stripe = blockIdx.x * 4 + wave;
    if (stripe >= STRIPES) return;
    int r0 = stripe * 16;
    int m = lane & 15, q = lane >> 4;
    float omt = 1.f - theta;

    f32x4 acc[8];
    #pragma unroll
    for (int nt = 0; nt < 8; nt++) acc[nt] = (f32x4){0.f, 0.f, 0.f, 0.f};

    const unsigned short* arow = s_in + (size_t)(r0 + m) * DIM + q * 8;
    #pragma unroll
    for (int ch = 0; ch < 4; ch++) {
        bf16x8 a = *(const bf16x8*)(arow + ch * 32);
        #pragma unroll
        for (int nt = 0; nt < 8; nt++) {
            bf16x8 b = *(const bf16x8*)(wp + (((nt * 4 + ch) * 64 + lane) << 3));
            acc[nt] = __builtin_amdgcn_mfma_f32_16x16x32_bf16(a, b, acc[nt], 0, 0, 0);
        }
    }

    #pragma unroll
    for (int nt = 0; nt < 8; nt++) {
        int col = nt * 16 + m;
        #pragma unroll
        for (int r = 0; r < 4; r++) {
            int row = r0 + q * 4 + r;
            size_t idx = (size_t)row * DIM + col;
            float sup = bf2f(s_in[idx]);
            float hp  = bf2f(hprev[idx]);
            float o = theta * acc[nt][r] + omt * sup + hp;
            hout[idx] = f2bf(fmaxf(o, 0.f));
        }
    }
}

// ===== MFMA output GEMM + log_softmax =====
__global__ __launch_bounds__(256) void k_out_mfma(
    const unsigned short* __restrict__ h, const unsigned short* __restrict__ wp,
    const float* __restrict__ bo, float* __restrict__ out) {
    int wave = threadIdx.x >> 6, lane = threadIdx.x & 63;
    int stripe = blockIdx.x * 4 + wave;
    if (stripe >= STRIPES) return;
    int r0 = stripe * 16;
    int m = lane & 15, q = lane >> 4;

    f32x4 acc[4];
    #pragma unroll
    for (int nt = 0; nt < 4; nt++) acc[nt] = (f32x4){0.f, 0.f, 0.f, 0.f};

    const unsigned short* arow = h + (size_t)(r0 + m) * DIM + q * 8;
    #pragma unroll
    for (int ch = 0; ch < 4; ch++) {
        bf16x8 a = *(const bf16x8*)(arow + ch * 32);
        #pragma unroll
        for (int nt = 0; nt < 4; nt++) {
            bf16x8 b = *(const bf16x8*)(wp + (((nt * 4 + ch) * 64 + lane) << 3));
            acc[nt] = __builtin_amdgcn_mfma_f32_16x16x32_bf16(a, b, acc[nt], 0, 0, 0);
        }
    }

    float v[4][4];
    #pragma unroll
    for (int nt = 0; nt < 4; nt++) {
        float bias = bo[nt * 16 + m];
        #pragma unroll
        for (int r = 0; r < 4; r++) v[nt][r] = acc[nt][r] + bias;
    }
    #pragma unroll
    for (int r = 0; r < 4; r++) {
        float mx = fmaxf(fmaxf(v[0][r], v[1][r]), fmaxf(v[2][r], v[3][r]));
        #pragma unroll
        for (int off = 1; off < 16; off <<= 1) mx = fmaxf(mx, __shfl_xor(mx, off));
        float s = 0.f;
        #pragma unroll
        for (int nt = 0; nt < 4; nt++) s += __expf(v[nt][r] - mx);
        #pragma unroll
        for (int off = 1; off < 16; off <<= 1) s += __shfl_xor(s, off);
        float lse = mx + logf(s);
        int row = r0 + q * 4 + r;
        #pragma unroll
        for (int nt = 0; nt < 4; nt++)
            out[(size_t)row * NCLS + nt * 16 + m] = v[nt][r] - lse;
    }
}

extern "C" void kernel_launch(void* const* d_in, const int* in_sizes, int n_in,
                              void* d_out, int out_size, void* d_ws, size_t ws_size,
                              hipStream_t stream) {
    const float* x    = (const float*)d_in[0];
    const int*   esrc = (const int*)d_in[1];
    const int*   edst = (const int*)d_in[2];
    const float* ew   = (const float*)d_in[3];
    const float* w_in = (const float*)d_in[4];
    const float* b_in = (const float*)d_in[5];
    const float* gcnw = (const float*)d_in[6];   // [4,128,128]
    const float* wout = (const float*)d_in[7];
    const float* bout = (const float*)d_in[8];
    float* out = (float*)d_out;

    // workspace layout
    unsigned short* h0 = (unsigned short*)d_ws;        // NF ushorts each
    unsigned short* hA = h0 + NF;
    unsigned short* hB = hA + NF;
    unsigned short* hi = hB + NF;
    unsigned short* wp = hi + NF;                      // 90112 ushorts packed W
    unsigned int* colw = (unsigned int*)(wp + 90112);  // E uints (packed src|w)
    int2* ebuf = (int2*)(colw + N_EDGES);              // E int2 (bucket-grouped)
    int*  row_ptr       = (int*)(ebuf + N_EDGES);      // N+1
    int*  deg           = row_ptr + (N_NODES + 1);     // N
    int*  blocksum      = deg + N_NODES;               // SCAN_B
    int*  bucket_cnt    = blocksum + SCAN_B;           // NB
    int*  bucket_base   = bucket_cnt + NB;             // NB+1
    int*  bucket_cursor = bucket_base + (NB + 1);      // NB

    const int PART_B = (N_EDGES + CHUNK - 1) / CHUNK;  // 782
    const int MFMA_BLOCKS = (STRIPES + 3) / 4;
    const int SPMM_BLOCKS = (N_NODES / 32) * 8;        // 25000

    // ---- weight pack ----
    k_prepw<<<(90112 + 255) / 256, 256, 0, stream>>>(gcnw, wout, w_in, wp);

    // ---- bucketed CSR build ----
    (void)hipMemsetAsync(bucket_cnt, 0, NB * sizeof(int), stream);
    k_hist<<<PART_B, 256, 0, stream>>>(edst, bucket_cnt);
    k_scanb<<<1, 512, 0, stream>>>(bucket_cnt, bucket_base, bucket_cursor);
    k_part<<<PART_B, 256, 0, stream>>>(esrc, edst, ew, bucket_cursor, ebuf);
    k_deg<<<NB, 256, 0, stream>>>(ebuf, bucket_base, deg);
    k_scan1<<<SCAN_B, 1024, 0, stream>>>(deg, row_ptr, blocksum);
    k_scan2<<<1, 128, 0, stream>>>(blocksum);
    k_scan3<<<SCAN_B, 1024, 0, stream>>>(row_ptr, blocksum);
    k_scatter2<<<NB, 256, 0, stream>>>(ebuf, bucket_base, row_ptr, colw);

    // h0 = relu(x @ w_in + b_in)
    k_in_mfma<<<MFMA_BLOCKS, 256, 0, stream>>>(x, wp + 73728, b_in, h0);

    const unsigned short* hprev = h0;
    unsigned short* bufs[2] = {hA, hB};
    for (int l = 0; l < 4; l++) {
        float theta = logf(0.5f / (float)(l + 2) + 1.0f);
        k_spmm_xcd<<<SPMM_BLOCKS, 256, 0, stream>>>(row_ptr, colw, hprev, h0, hi);
        unsigned short* hnew = bufs[l & 1];
        k_layer_mfma<<<MFMA_BLOCKS, 256, 0, stream>>>(hi, hprev, wp + (size_t)l * 16384,
                                                      hnew, theta);
        hprev = hnew;
    }

    // out = log_softmax(h @ w_out + b_out)
    k_out_mfma<<<MFMA_BLOCKS, 256, 0, stream>>>(hprev, wp + 65536, bout, out);
}